// Round 13
// baseline (345.796 us; speedup 1.0000x reference)
//
#include <hip/hip_runtime.h>
#include <hip/hip_bf16.h>

#define HDIM 1024
#define SEQ 2048
#define BATCH 16
#define M_TOT (SEQ*BATCH)   // 32768
#define NBLK 4              // N split into 4 chunks of 256
#define BM 256
#define BN 256
#define BKT 64              // K-tile depth
#define NT (HDIM/BKT)       // 16 K-tiles

// prep_all grid layout
#define NB_ENC ((M_TOT*HDIM)/(8*256))   // 16384
#define NB_WE  ((HDIM*HDIM)/(8*256))    // 512
#define NB_QK  (HDIM)                   // 1024

typedef __attribute__((ext_vector_type(8))) short short8;
typedef __attribute__((ext_vector_type(4))) float f32x4;

typedef const void __attribute__((address_space(1))) gvoid_t;
typedef void __attribute__((address_space(3))) svoid_t;
#define GLD16(gp, lp) __builtin_amdgcn_global_load_lds((gvoid_t*)(gp), (svoid_t*)(lp), 16, 0, 0)
#define VMC(N) asm volatile("s_waitcnt vmcnt(" #N ")" ::: "memory")

static __device__ __forceinline__ unsigned short f2bf(float f) {
    unsigned int x = __float_as_uint(f);
    unsigned int r = (x + 0x7FFFu + ((x >> 16) & 1u)) >> 16;  // RNE
    return (unsigned short)r;
}

// ---------------- kernel 1: fused prep = conv_enc + conv_we + qk ----------------
__global__ __launch_bounds__(256) void prep_all(const float* __restrict__ hidden,
                                                const float* __restrict__ enc,
                                                const float* __restrict__ attn_w,
                                                const float* __restrict__ attn_b,
                                                float* __restrict__ q,
                                                __hip_bfloat16* __restrict__ web,
                                                __hip_bfloat16* __restrict__ encb) {
    int bid = blockIdx.x;
    if (bid < NB_ENC) {
        size_t i0 = ((size_t)bid * 256 + threadIdx.x) * 8;
        const float4* s = reinterpret_cast<const float4*>(enc + i0);
        float4 a = s[0], b = s[1];
        union { unsigned short u[8]; short8 v; } cv;
        cv.u[0] = f2bf(a.x); cv.u[1] = f2bf(a.y); cv.u[2] = f2bf(a.z); cv.u[3] = f2bf(a.w);
        cv.u[4] = f2bf(b.x); cv.u[5] = f2bf(b.y); cv.u[6] = f2bf(b.z); cv.u[7] = f2bf(b.w);
        *reinterpret_cast<short8*>((unsigned short*)encb + i0) = cv.v;
        return;
    }
    if (bid < NB_ENC + NB_WE) {
        size_t i0 = ((size_t)(bid - NB_ENC) * 256 + threadIdx.x) * 8;
        int n = (int)(i0 >> 10);
        int h = (int)(i0 & 1023);
        const float4* src = reinterpret_cast<const float4*>(attn_w + (size_t)n * (2 * HDIM) + HDIM + h);
        float4 a = src[0], b = src[1];
        union { unsigned short u[8]; short8 v; } cv;
        cv.u[0] = f2bf(a.x); cv.u[1] = f2bf(a.y); cv.u[2] = f2bf(a.z); cv.u[3] = f2bf(a.w);
        cv.u[4] = f2bf(b.x); cv.u[5] = f2bf(b.y); cv.u[6] = f2bf(b.z); cv.u[7] = f2bf(b.w);
        *reinterpret_cast<short8*>((unsigned short*)web + i0) = cv.v;
        return;
    }
    int k = bid - (NB_ENC + NB_WE);   // 0..1023
    int tid = threadIdx.x;
    const float* w = attn_w + (size_t)k * (2 * HDIM);
    float p[BATCH];
#pragma unroll
    for (int b = 0; b < BATCH; b++) p[b] = 0.f;
    for (int h = tid; h < HDIM; h += 256) {
        float wv = w[h];
#pragma unroll
        for (int b = 0; b < BATCH; b++) p[b] += hidden[b * HDIM + h] * wv;
    }
#pragma unroll
    for (int b = 0; b < BATCH; b++) {
        for (int off = 32; off; off >>= 1) p[b] += __shfl_down(p[b], off);
    }
    __shared__ float red[4][BATCH];
    int lane = tid & 63, wid = tid >> 6;
    if (lane == 0) {
#pragma unroll
        for (int b = 0; b < BATCH; b++) red[wid][b] = p[b];
    }
    __syncthreads();
    if (tid < BATCH) {
        float s = red[0][tid] + red[1][tid] + red[2][tid] + red[3][tid] + attn_b[k];
        q[(size_t)tid * HDIM + k] = s;
    }
}

// ---------------- kernel 2: 256x256 GEMM, 1 barrier/tile, wave-parity staggered clusters ----
// LDS map (bytes): A[par][half] = par*32768 + half*16384 (64KB);
//                  B[buf][half] = 65536 + buf*32768 + half*16384, buf in 0..2 (96KB). 160KB total.
// Swizzle involution within each 128B row: byte ^= ((row&7)<<4). Applied to global src + ds_read.
// Clusters within a tile are independent (disjoint acc, all frags resident at tile entry), so
// even waves run order 0,1,2,3 and odd waves 2,3,0,1 -> DS-pipe and MFMA-pipe overlap across
// parities instead of convoying. Staging slots + vmcnt ledger identical to the verified R11.
__global__ __launch_bounds__(512, 2) void gemm8(const __hip_bfloat16* __restrict__ encb,
                                                const __hip_bfloat16* __restrict__ web,
                                                const float* __restrict__ qv,
                                                const float* __restrict__ score_w,
                                                float* __restrict__ part) {
    __shared__ __align__(16) char pool[163840];

    int tid = threadIdx.x;
    int lane = tid & 63;
    int wid = tid >> 6;        // 0..7
    int wr = wid >> 2;         // 0..1  M half
    int wc = wid & 3;          // 0..3  N quarter

    // XCD-bijective swizzle: 512 blocks = 8 XCDs x 64; same-bm (A-panel) blocks contiguous per XCD
    int bid = blockIdx.x;
    int lin = (bid & 7) * 64 + (bid >> 3);
    int bm = lin >> 2;         // 0..127
    int bn = lin & 3;          // 0..3
    int m0 = bm * BM, n0 = bn * BN;

    // ---- staging thread constants (pre-swizzled global source) ----
    int srow = tid >> 3;                                   // 0..63
    int scolb = (((tid & 7) ^ ((tid >> 3) & 7)) << 4);     // swizzled byte col 0..127
    const char* eb = (const char*)encb;
    const char* wb = (const char*)web;

    auto STG = [&](const char* g, int ldsoff) {
        GLD16(g + (size_t)srow * 2048 + scolb, pool + ldsoff + wid * 1024);
        GLD16(g + (size_t)(srow + 64) * 2048 + scolb, pool + ldsoff + 8192 + wid * 1024);
    };
    auto APTR = [&](int kt, int h) { return eb + ((size_t)(m0 + h * 128) * HDIM + kt * BKT) * 2; };
    auto BPTR = [&](int kt, int h) { return wb + ((size_t)(n0 + h * 128) * HDIM + kt * BKT) * 2; };
#define ALDS(par, h) ((par) * 32768 + (h) * 16384)
#define BLDS(buf, h) (65536 + (buf) * 32768 + (h) * 16384)

    // ---- fragment-read constants (swizzled ds_read addresses) ----
    int lq = lane & 15, lh = lane >> 4;
    int flip = (lane & 7) << 4;
    int pks0 = lq * 128 + ((lh * 16) ^ flip);
    int pks1 = lq * 128 + (((64 + lh * 16)) ^ flip);
    int aFB = wr * 16384;                                   // + par*32768
    int bOFF = (wc >> 1) * 16384 + (wc & 1) * 8192;         // within B buffer

    f32x4 acc[8][4];
#pragma unroll
    for (int i = 0; i < 8; i++)
#pragma unroll
        for (int j = 0; j < 4; j++) acc[i][j] = (f32x4)0.f;
    short8 br[4][2];

#define RD8(off) (*reinterpret_cast<const short8*>(pool + (off)))

    // cluster Q of tile: A-frag reads for mi=2Q,2Q+1 (+ B full when FIRST) + stage + 16 MFMA
#define CLUSTER(Q, PAR, BB, FIRST, STAGE_STMT)                                            \
    {                                                                                     \
        if (FIRST) {                                                                      \
            _Pragma("unroll") for (int nj = 0; nj < 4; ++nj) {                            \
                br[nj][0] = RD8(65536 + (BB) * 32768 + bOFF + nj * 2048 + pks0);          \
                br[nj][1] = RD8(65536 + (BB) * 32768 + bOFF + nj * 2048 + pks1);          \
            }                                                                             \
        }                                                                                 \
        short8 a0k0 = RD8(aFB + (PAR) * 32768 + (2 * (Q)) * 2048 + pks0);                 \
        short8 a0k1 = RD8(aFB + (PAR) * 32768 + (2 * (Q)) * 2048 + pks1);                 \
        short8 a1k0 = RD8(aFB + (PAR) * 32768 + (2 * (Q) + 1) * 2048 + pks0);             \
        short8 a1k1 = RD8(aFB + (PAR) * 32768 + (2 * (Q) + 1) * 2048 + pks1);             \
        STAGE_STMT;                                                                       \
        __builtin_amdgcn_s_setprio(1);                                                    \
        _Pragma("unroll") for (int nj = 0; nj < 4; ++nj) {                                \
            acc[2 * (Q)][nj] = __builtin_amdgcn_mfma_f32_16x16x32_bf16(a0k0, br[nj][0], acc[2 * (Q)][nj], 0, 0, 0); \
            acc[2 * (Q)][nj] = __builtin_amdgcn_mfma_f32_16x16x32_bf16(a0k1, br[nj][1], acc[2 * (Q)][nj], 0, 0, 0); \
            acc[2 * (Q) + 1][nj] = __builtin_amdgcn_mfma_f32_16x16x32_bf16(a1k0, br[nj][0], acc[2 * (Q) + 1][nj], 0, 0, 0); \
            acc[2 * (Q) + 1][nj] = __builtin_amdgcn_mfma_f32_16x16x32_bf16(a1k1, br[nj][1], acc[2 * (Q) + 1][nj], 0, 0, 0); \
        }                                                                                 \
        __builtin_amdgcn_s_setprio(0);                                                    \
    }

    // tile = 4 barrier-free clusters (order staggered by wave parity) + close {VMC; barrier}
#define TILE(PAR, BB, S1, S2, S3, S4, CLOSE)                                              \
    {                                                                                     \
        if ((wid & 1) == 0) {                                                             \
            CLUSTER(0, PAR, BB, 1, S1);                                                   \
            CLUSTER(1, PAR, BB, 0, S2);                                                   \
            CLUSTER(2, PAR, BB, 0, S3);                                                   \
            CLUSTER(3, PAR, BB, 0, S4);                                                   \
        } else {                                                                          \
            CLUSTER(2, PAR, BB, 1, S1);                                                   \
            CLUSTER(3, PAR, BB, 0, S2);                                                   \
            CLUSTER(0, PAR, BB, 0, S3);                                                   \
            CLUSTER(1, PAR, BB, 0, S4);                                                   \
        }                                                                                 \
        CLOSE;                                                                            \
        __builtin_amdgcn_s_barrier();                                                     \
        __builtin_amdgcn_sched_barrier(0);                                                \
    }

    // ---- prologue: stage A(0), B(0), B(1); land A(0)+B(0), keep B(1) in flight ----
    STG(APTR(0, 0), ALDS(0, 0));
    STG(APTR(0, 1), ALDS(0, 1));
    STG(BPTR(0, 0), BLDS(0, 0));
    STG(BPTR(0, 1), BLDS(0, 1));
    STG(BPTR(1, 0), BLDS(1, 0));
    STG(BPTR(1, 1), BLDS(1, 1));
    VMC(4);
    __builtin_amdgcn_s_barrier();
    __builtin_amdgcn_sched_barrier(0);

    // ---- main loop: 2 x 6 tiles (pattern period lcm(2,3)=6), then 4 peeled ----
#pragma unroll 1
    for (int J = 0; J < 2; ++J) {
        int t = 6 * J;
        TILE(0, 0, STG(APTR(t + 1, 0), ALDS(1, 0)), STG(APTR(t + 1, 1), ALDS(1, 1)),
                   STG(BPTR(t + 2, 0), BLDS(2, 0)), STG(BPTR(t + 2, 1), BLDS(2, 1)), VMC(4));
        TILE(1, 1, STG(APTR(t + 2, 0), ALDS(0, 0)), STG(APTR(t + 2, 1), ALDS(0, 1)),
                   STG(BPTR(t + 3, 0), BLDS(0, 0)), STG(BPTR(t + 3, 1), BLDS(0, 1)), VMC(4));
        TILE(0, 2, STG(APTR(t + 3, 0), ALDS(1, 0)), STG(APTR(t + 3, 1), ALDS(1, 1)),
                   STG(BPTR(t + 4, 0), BLDS(1, 0)), STG(BPTR(t + 4, 1), BLDS(1, 1)), VMC(4));
        TILE(1, 0, STG(APTR(t + 4, 0), ALDS(0, 0)), STG(APTR(t + 4, 1), ALDS(0, 1)),
                   STG(BPTR(t + 5, 0), BLDS(2, 0)), STG(BPTR(t + 5, 1), BLDS(2, 1)), VMC(4));
        TILE(0, 1, STG(APTR(t + 5, 0), ALDS(1, 0)), STG(APTR(t + 5, 1), ALDS(1, 1)),
                   STG(BPTR(t + 6, 0), BLDS(0, 0)), STG(BPTR(t + 6, 1), BLDS(0, 1)), VMC(4));
        TILE(1, 2, STG(APTR(t + 6, 0), ALDS(0, 0)), STG(APTR(t + 6, 1), ALDS(0, 1)),
                   STG(BPTR(t + 7, 0), BLDS(1, 0)), STG(BPTR(t + 7, 1), BLDS(1, 1)), VMC(4));
    }
    // tiles 12..15
    TILE(0, 0, STG(APTR(13, 0), ALDS(1, 0)), STG(APTR(13, 1), ALDS(1, 1)),
               STG(BPTR(14, 0), BLDS(2, 0)), STG(BPTR(14, 1), BLDS(2, 1)), VMC(4));
    TILE(1, 1, STG(APTR(14, 0), ALDS(0, 0)), STG(APTR(14, 1), ALDS(0, 1)),
               STG(BPTR(15, 0), BLDS(0, 0)), STG(BPTR(15, 1), BLDS(0, 1)), VMC(4));
    TILE(0, 2, STG(APTR(15, 0), ALDS(1, 0)), STG(APTR(15, 1), ALDS(1, 1)), , , VMC(0));
    TILE(1, 0, , , , , );

    // ---- fused epilogue (aliases pool) ----
    float* q_lds = reinterpret_cast<float*>(pool);            // [16][256]
    float* sc_lds = reinterpret_cast<float*>(pool + 16384);   // [256]
    float* eng = reinterpret_cast<float*>(pool + 17408);      // [4][256]
    {
        int qb = tid >> 5;            // 0..15
        int kl = (tid & 31) * 8;      // 0..248
        const float4* src = reinterpret_cast<const float4*>(qv + (size_t)qb * HDIM + n0 + kl);
        float4 v0 = src[0], v1 = src[1];
        *reinterpret_cast<float4*>(&q_lds[qb * 256 + kl]) = v0;
        *reinterpret_cast<float4*>(&q_lds[qb * 256 + kl + 4]) = v1;
        if (tid < BN) sc_lds[tid] = score_w[n0 + tid];
    }
    __syncthreads();

#pragma unroll
    for (int mi = 0; mi < 8; ++mi) {
#pragma unroll
        for (int r = 0; r < 4; ++r) {
            int b = lh * 4 + r;       // row-within-16 == batch index
            float s = 0.f;
#pragma unroll
            for (int nj = 0; nj < 4; ++nj) {
                int kl = wc * 64 + nj * 16 + lq;
                float v = acc[mi][nj][r] + q_lds[b * 256 + kl];
                float t = 1.f - 2.f / (__expf(2.f * v) + 1.f);  // tanh(v)
                s += sc_lds[kl] * t;
            }
            for (int off = 1; off < 16; off <<= 1) s += __shfl_xor(s, off);
            if (lq == 0) eng[wc * 256 + wr * 128 + mi * 16 + b] = s;
        }
    }
    __syncthreads();
    if (tid < BM) {
        float s = eng[tid] + eng[256 + tid] + eng[512 + tid] + eng[768 + tid];
        part[(size_t)bn * M_TOT + m0 + tid] = s;
    }
#undef CLUSTER
#undef TILE
#undef RD8
#undef ALDS
#undef BLDS
}

// ---------------- kernel 3: reduce partials + mask + softmax over S ----------------
__global__ __launch_bounds__(256) void softmax_kernel(const float* __restrict__ part,
                                                      const int* __restrict__ mask,
                                                      float* __restrict__ out) {
    int b = blockIdx.x;
    int tid = threadIdx.x;
    __shared__ float e_lds[SEQ];
    __shared__ float red[4], red2[4];
    int lane = tid & 63, wid = tid >> 6;
    float lmax = -3.4e38f;
    for (int it = 0; it < SEQ / 256; ++it) {
        int s = it * 256 + tid;
        size_t m = (size_t)s * BATCH + b;
        float e = 0.f;
#pragma unroll
        for (int c = 0; c < NBLK; c++) e += part[(size_t)c * M_TOT + m];
        if (mask[(size_t)b * SEQ + s]) e = -1e12f;
        e_lds[s] = e;
        lmax = fmaxf(lmax, e);
    }
    for (int off = 32; off; off >>= 1) lmax = fmaxf(lmax, __shfl_xor(lmax, off));
    if (lane == 0) red[wid] = lmax;
    __syncthreads();
    float gmax = fmaxf(fmaxf(red[0], red[1]), fmaxf(red[2], red[3]));
    float lsum = 0.f;
    for (int it = 0; it < SEQ / 256; ++it) {
        int s = it * 256 + tid;
        float p = __expf(e_lds[s] - gmax);
        e_lds[s] = p;
        lsum += p;
    }
    for (int off = 32; off; off >>= 1) lsum += __shfl_xor(lsum, off);
    if (lane == 0) red2[wid] = lsum;
    __syncthreads();
    float inv = 1.f / (red2[0] + red2[1] + red2[2] + red2[3]);
    for (int it = 0; it < SEQ / 256; ++it) {
        int s = it * 256 + tid;
        out[(size_t)b * SEQ + s] = e_lds[s] * inv;
    }
}

extern "C" void kernel_launch(void* const* d_in, const int* in_sizes, int n_in,
                              void* d_out, int out_size, void* d_ws, size_t ws_size,
                              hipStream_t stream) {
    const float* hidden   = (const float*)d_in[0];
    const float* enc      = (const float*)d_in[1];
    const int*   seq_mask = (const int*)d_in[2];
    const float* attn_w   = (const float*)d_in[3];
    const float* attn_b   = (const float*)d_in[4];
    const float* score_w  = (const float*)d_in[5];
    float* out = (float*)d_out;

    char* ws = (char*)d_ws;
    float* q = (float*)ws;                                        // 64 KB
    __hip_bfloat16* web = (__hip_bfloat16*)(ws + 65536);          // 2 MB
    float* part = (float*)(ws + 65536 + 2 * 1024 * 1024);         // 512 KB
    __hip_bfloat16* encb = (__hip_bfloat16*)(ws + 65536 + 3 * 1024 * 1024);  // 64 MB

    prep_all<<<dim3(NB_ENC + NB_WE + NB_QK), dim3(256), 0, stream>>>(hidden, enc, attn_w, attn_b, q, web, encb);
    gemm8<<<dim3(NBLK * (M_TOT / BM)), dim3(512), 0, stream>>>(encb, web, q, score_w, part);
    softmax_kernel<<<dim3(BATCH), dim3(256), 0, stream>>>(part, seq_mask, out);
}

// Round 14
// 118.594 us; speedup vs baseline: 2.9158x; 2.9158x over previous
//
#include <hip/hip_runtime.h>
#include <hip/hip_bf16.h>

#define HDIM 1024
#define SEQ 2048
#define BATCH 16
#define M_TOT (SEQ*BATCH)   // 32768
#define NBLK 4              // N split into 4 chunks of 256
#define BM 256
#define BN 256
#define BKT 64              // K-tile depth
#define NT (HDIM/BKT)       // 16 K-tiles

// prep_all grid layout
#define NB_ENC ((M_TOT*HDIM)/(8*256))   // 16384
#define NB_WE  ((HDIM*HDIM)/(8*256))    // 512
#define NB_QK  (HDIM)                   // 1024

typedef __attribute__((ext_vector_type(8))) short short8;
typedef __attribute__((ext_vector_type(4))) float f32x4;

typedef const void __attribute__((address_space(1))) gvoid_t;
typedef void __attribute__((address_space(3))) svoid_t;
#define GLD16(gp, lp) __builtin_amdgcn_global_load_lds((gvoid_t*)(gp), (svoid_t*)(lp), 16, 0, 0)
#define VMC(N) asm volatile("s_waitcnt vmcnt(" #N ")" ::: "memory")

static __device__ __forceinline__ unsigned short f2bf(float f) {
    unsigned int x = __float_as_uint(f);
    unsigned int r = (x + 0x7FFFu + ((x >> 16) & 1u)) >> 16;  // RNE
    return (unsigned short)r;
}

// ---------------- kernel 1: fused prep = conv_enc + conv_we + qk ----------------
__global__ __launch_bounds__(256) void prep_all(const float* __restrict__ hidden,
                                                const float* __restrict__ enc,
                                                const float* __restrict__ attn_w,
                                                const float* __restrict__ attn_b,
                                                float* __restrict__ q,
                                                __hip_bfloat16* __restrict__ web,
                                                __hip_bfloat16* __restrict__ encb) {
    int bid = blockIdx.x;
    if (bid < NB_ENC) {
        size_t i0 = ((size_t)bid * 256 + threadIdx.x) * 8;
        const float4* s = reinterpret_cast<const float4*>(enc + i0);
        float4 a = s[0], b = s[1];
        union { unsigned short u[8]; short8 v; } cv;
        cv.u[0] = f2bf(a.x); cv.u[1] = f2bf(a.y); cv.u[2] = f2bf(a.z); cv.u[3] = f2bf(a.w);
        cv.u[4] = f2bf(b.x); cv.u[5] = f2bf(b.y); cv.u[6] = f2bf(b.z); cv.u[7] = f2bf(b.w);
        *reinterpret_cast<short8*>((unsigned short*)encb + i0) = cv.v;
        return;
    }
    if (bid < NB_ENC + NB_WE) {
        size_t i0 = ((size_t)(bid - NB_ENC) * 256 + threadIdx.x) * 8;
        int n = (int)(i0 >> 10);
        int h = (int)(i0 & 1023);
        const float4* src = reinterpret_cast<const float4*>(attn_w + (size_t)n * (2 * HDIM) + HDIM + h);
        float4 a = src[0], b = src[1];
        union { unsigned short u[8]; short8 v; } cv;
        cv.u[0] = f2bf(a.x); cv.u[1] = f2bf(a.y); cv.u[2] = f2bf(a.z); cv.u[3] = f2bf(a.w);
        cv.u[4] = f2bf(b.x); cv.u[5] = f2bf(b.y); cv.u[6] = f2bf(b.z); cv.u[7] = f2bf(b.w);
        *reinterpret_cast<short8*>((unsigned short*)web + i0) = cv.v;
        return;
    }
    int k = bid - (NB_ENC + NB_WE);   // 0..1023
    int tid = threadIdx.x;
    const float* w = attn_w + (size_t)k * (2 * HDIM);
    float p[BATCH];
#pragma unroll
    for (int b = 0; b < BATCH; b++) p[b] = 0.f;
    for (int h = tid; h < HDIM; h += 256) {
        float wv = w[h];
#pragma unroll
        for (int b = 0; b < BATCH; b++) p[b] += hidden[b * HDIM + h] * wv;
    }
#pragma unroll
    for (int b = 0; b < BATCH; b++) {
        for (int off = 32; off; off >>= 1) p[b] += __shfl_down(p[b], off);
    }
    __shared__ float red[4][BATCH];
    int lane = tid & 63, wid = tid >> 6;
    if (lane == 0) {
#pragma unroll
        for (int b = 0; b < BATCH; b++) red[wid][b] = p[b];
    }
    __syncthreads();
    if (tid < BATCH) {
        float s = red[0][tid] + red[1][tid] + red[2][tid] + red[3][tid] + attn_b[k];
        q[(size_t)tid * HDIM + k] = s;
    }
}

// ---------------- kernel 2: 256x256 GEMM, 1 barrier/tile (B triple-buffered) ----------------
// LDS map (bytes): A[par][half] = par*32768 + half*16384 (64KB);
//                  B[buf][half] = 65536 + buf*32768 + half*16384, buf in 0..2 (96KB). 160KB total.
// Swizzle involution within each 128B row: byte ^= ((row&7)<<4). Applied to global src + ds_read.
// Per tile t: read B(t) from B[t%3] (regs) + A(t) from A[t&1]; stage A(t+1)->A[par^1],
// B(t+2)->B[(t+2)%3] (never the live/next buffer -> NO interior barrier needed).
// Close: VMC(4) (drains A(t+1)+B(t+1), keeps B(t+2) in flight) + one s_barrier.
__global__ __launch_bounds__(512, 2) void gemm8(const __hip_bfloat16* __restrict__ encb,
                                                const __hip_bfloat16* __restrict__ web,
                                                const float* __restrict__ qv,
                                                const float* __restrict__ score_w,
                                                float* __restrict__ part) {
    __shared__ __align__(16) char pool[163840];

    int tid = threadIdx.x;
    int lane = tid & 63;
    int wid = tid >> 6;        // 0..7
    int wr = wid >> 2;         // 0..1  M half
    int wc = wid & 3;          // 0..3  N quarter

    // XCD-bijective swizzle: 512 blocks = 8 XCDs x 64; same-bm (A-panel) blocks contiguous per XCD
    int bid = blockIdx.x;
    int lin = (bid & 7) * 64 + (bid >> 3);
    int bm = lin >> 2;         // 0..127
    int bn = lin & 3;          // 0..3
    int m0 = bm * BM, n0 = bn * BN;

    // ---- staging thread constants (pre-swizzled global source) ----
    int srow = tid >> 3;                                   // 0..63
    int scolb = (((tid & 7) ^ ((tid >> 3) & 7)) << 4);     // swizzled byte col 0..127
    const char* eb = (const char*)encb;
    const char* wb = (const char*)web;

    auto STG = [&](const char* g, int ldsoff) {
        GLD16(g + (size_t)srow * 2048 + scolb, pool + ldsoff + wid * 1024);
        GLD16(g + (size_t)(srow + 64) * 2048 + scolb, pool + ldsoff + 8192 + wid * 1024);
    };
    auto APTR = [&](int kt, int h) { return eb + ((size_t)(m0 + h * 128) * HDIM + kt * BKT) * 2; };
    auto BPTR = [&](int kt, int h) { return wb + ((size_t)(n0 + h * 128) * HDIM + kt * BKT) * 2; };
#define ALDS(par, h) ((par) * 32768 + (h) * 16384)
#define BLDS(buf, h) (65536 + (buf) * 32768 + (h) * 16384)

    // ---- fragment-read constants (swizzled ds_read addresses) ----
    int lq = lane & 15, lh = lane >> 4;
    int flip = (lane & 7) << 4;
    int pks0 = lq * 128 + ((lh * 16) ^ flip);
    int pks1 = lq * 128 + (((64 + lh * 16)) ^ flip);
    int aFB = wr * 16384;                                   // + par*32768
    int bOFF = (wc >> 1) * 16384 + (wc & 1) * 8192;         // within B buffer

    f32x4 acc[8][4];
#pragma unroll
    for (int i = 0; i < 8; i++)
#pragma unroll
        for (int j = 0; j < 4; j++) acc[i][j] = (f32x4)0.f;
    short8 br[4][2];

#define RD8(off) (*reinterpret_cast<const short8*>(pool + (off)))

    // cluster Q of tile: frag reads (B full at Q==0 from buf BB) + stage + 16 MFMA. No barriers.
#define CLUSTER(Q, PAR, BB, STAGE_STMT)                                                   \
    {                                                                                     \
        if ((Q) == 0) {                                                                   \
            _Pragma("unroll") for (int nj = 0; nj < 4; ++nj) {                            \
                br[nj][0] = RD8(65536 + (BB) * 32768 + bOFF + nj * 2048 + pks0);          \
                br[nj][1] = RD8(65536 + (BB) * 32768 + bOFF + nj * 2048 + pks1);          \
            }                                                                             \
        }                                                                                 \
        short8 a0k0 = RD8(aFB + (PAR) * 32768 + (2 * (Q)) * 2048 + pks0);                 \
        short8 a0k1 = RD8(aFB + (PAR) * 32768 + (2 * (Q)) * 2048 + pks1);                 \
        short8 a1k0 = RD8(aFB + (PAR) * 32768 + (2 * (Q) + 1) * 2048 + pks0);             \
        short8 a1k1 = RD8(aFB + (PAR) * 32768 + (2 * (Q) + 1) * 2048 + pks1);             \
        STAGE_STMT;                                                                       \
        __builtin_amdgcn_s_setprio(1);                                                    \
        _Pragma("unroll") for (int nj = 0; nj < 4; ++nj) {                                \
            acc[2 * (Q)][nj] = __builtin_amdgcn_mfma_f32_16x16x32_bf16(a0k0, br[nj][0], acc[2 * (Q)][nj], 0, 0, 0); \
            acc[2 * (Q)][nj] = __builtin_amdgcn_mfma_f32_16x16x32_bf16(a0k1, br[nj][1], acc[2 * (Q)][nj], 0, 0, 0); \
            acc[2 * (Q) + 1][nj] = __builtin_amdgcn_mfma_f32_16x16x32_bf16(a1k0, br[nj][0], acc[2 * (Q) + 1][nj], 0, 0, 0); \
            acc[2 * (Q) + 1][nj] = __builtin_amdgcn_mfma_f32_16x16x32_bf16(a1k1, br[nj][1], acc[2 * (Q) + 1][nj], 0, 0, 0); \
        }                                                                                 \
        __builtin_amdgcn_s_setprio(0);                                                    \
    }

    // tile = 4 barrier-free clusters + close {counted VMC; one barrier}
#define TILE(PAR, BB, S1, S2, S3, S4, CLOSE)                                              \
    {                                                                                     \
        CLUSTER(0, PAR, BB, S1);                                                          \
        CLUSTER(1, PAR, BB, S2);                                                          \
        CLUSTER(2, PAR, BB, S3);                                                          \
        CLUSTER(3, PAR, BB, S4);                                                          \
        CLOSE;                                                                            \
        __builtin_amdgcn_s_barrier();                                                     \
        __builtin_amdgcn_sched_barrier(0);                                                \
    }

    // ---- prologue: stage A(0), B(0), B(1); land A(0)+B(0), keep B(1) in flight ----
    STG(APTR(0, 0), ALDS(0, 0));
    STG(APTR(0, 1), ALDS(0, 1));
    STG(BPTR(0, 0), BLDS(0, 0));
    STG(BPTR(0, 1), BLDS(0, 1));
    STG(BPTR(1, 0), BLDS(1, 0));
    STG(BPTR(1, 1), BLDS(1, 1));
    VMC(4);
    __builtin_amdgcn_s_barrier();
    __builtin_amdgcn_sched_barrier(0);

    // ---- main loop: 2 x 6 tiles (pattern period lcm(2,3)=6), then 4 peeled ----
#pragma unroll 1
    for (int J = 0; J < 2; ++J) {
        int t = 6 * J;
        TILE(0, 0, STG(APTR(t + 1, 0), ALDS(1, 0)), STG(APTR(t + 1, 1), ALDS(1, 1)),
                   STG(BPTR(t + 2, 0), BLDS(2, 0)), STG(BPTR(t + 2, 1), BLDS(2, 1)), VMC(4));
        TILE(1, 1, STG(APTR(t + 2, 0), ALDS(0, 0)), STG(APTR(t + 2, 1), ALDS(0, 1)),
                   STG(BPTR(t + 3, 0), BLDS(0, 0)), STG(BPTR(t + 3, 1), BLDS(0, 1)), VMC(4));
        TILE(0, 2, STG(APTR(t + 3, 0), ALDS(1, 0)), STG(APTR(t + 3, 1), ALDS(1, 1)),
                   STG(BPTR(t + 4, 0), BLDS(1, 0)), STG(BPTR(t + 4, 1), BLDS(1, 1)), VMC(4));
        TILE(1, 0, STG(APTR(t + 4, 0), ALDS(0, 0)), STG(APTR(t + 4, 1), ALDS(0, 1)),
                   STG(BPTR(t + 5, 0), BLDS(2, 0)), STG(BPTR(t + 5, 1), BLDS(2, 1)), VMC(4));
        TILE(0, 1, STG(APTR(t + 5, 0), ALDS(1, 0)), STG(APTR(t + 5, 1), ALDS(1, 1)),
                   STG(BPTR(t + 6, 0), BLDS(0, 0)), STG(BPTR(t + 6, 1), BLDS(0, 1)), VMC(4));
        TILE(1, 2, STG(APTR(t + 6, 0), ALDS(0, 0)), STG(APTR(t + 6, 1), ALDS(0, 1)),
                   STG(BPTR(t + 7, 0), BLDS(1, 0)), STG(BPTR(t + 7, 1), BLDS(1, 1)), VMC(4));
    }
    // tiles 12..15
    TILE(0, 0, STG(APTR(13, 0), ALDS(1, 0)), STG(APTR(13, 1), ALDS(1, 1)),
               STG(BPTR(14, 0), BLDS(2, 0)), STG(BPTR(14, 1), BLDS(2, 1)), VMC(4));
    TILE(1, 1, STG(APTR(14, 0), ALDS(0, 0)), STG(APTR(14, 1), ALDS(0, 1)),
               STG(BPTR(15, 0), BLDS(0, 0)), STG(BPTR(15, 1), BLDS(0, 1)), VMC(4));
    TILE(0, 2, STG(APTR(15, 0), ALDS(1, 0)), STG(APTR(15, 1), ALDS(1, 1)), , , VMC(0));
    TILE(1, 0, , , , , );

    // ---- fused epilogue (aliases pool) ----
    float* q_lds = reinterpret_cast<float*>(pool);            // [16][256]
    float* sc_lds = reinterpret_cast<float*>(pool + 16384);   // [256]
    float* eng = reinterpret_cast<float*>(pool + 17408);      // [4][256]
    {
        int qb = tid >> 5;            // 0..15
        int kl = (tid & 31) * 8;      // 0..248
        const float4* src = reinterpret_cast<const float4*>(qv + (size_t)qb * HDIM + n0 + kl);
        float4 v0 = src[0], v1 = src[1];
        *reinterpret_cast<float4*>(&q_lds[qb * 256 + kl]) = v0;
        *reinterpret_cast<float4*>(&q_lds[qb * 256 + kl + 4]) = v1;
        if (tid < BN) sc_lds[tid] = score_w[n0 + tid];
    }
    __syncthreads();

#pragma unroll
    for (int mi = 0; mi < 8; ++mi) {
#pragma unroll
        for (int r = 0; r < 4; ++r) {
            int b = lh * 4 + r;       // row-within-16 == batch index
            float s = 0.f;
#pragma unroll
            for (int nj = 0; nj < 4; ++nj) {
                int kl = wc * 64 + nj * 16 + lq;
                float v = acc[mi][nj][r] + q_lds[b * 256 + kl];
                float t = 1.f - 2.f / (__expf(2.f * v) + 1.f);  // tanh(v)
                s += sc_lds[kl] * t;
            }
            for (int off = 1; off < 16; off <<= 1) s += __shfl_xor(s, off);
            if (lq == 0) eng[wc * 256 + wr * 128 + mi * 16 + b] = s;
        }
    }
    __syncthreads();
    if (tid < BM) {
        float s = eng[tid] + eng[256 + tid] + eng[512 + tid] + eng[768 + tid];
        part[(size_t)bn * M_TOT + m0 + tid] = s;
    }
#undef CLUSTER
#undef TILE
#undef RD8
#undef ALDS
#undef BLDS
}

// ---------------- kernel 3: reduce partials + mask + softmax over S ----------------
__global__ __launch_bounds__(256) void softmax_kernel(const float* __restrict__ part,
                                                      const int* __restrict__ mask,
                                                      float* __restrict__ out) {
    int b = blockIdx.x;
    int tid = threadIdx.x;
    __shared__ float e_lds[SEQ];
    __shared__ float red[4], red2[4];
    int lane = tid & 63, wid = tid >> 6;
    float lmax = -3.4e38f;
    for (int it = 0; it < SEQ / 256; ++it) {
        int s = it * 256 + tid;
        size_t m = (size_t)s * BATCH + b;
        float e = 0.f;
#pragma unroll
        for (int c = 0; c < NBLK; c++) e += part[(size_t)c * M_TOT + m];
        if (mask[(size_t)b * SEQ + s]) e = -1e12f;
        e_lds[s] = e;
        lmax = fmaxf(lmax, e);
    }
    for (int off = 32; off; off >>= 1) lmax = fmaxf(lmax, __shfl_xor(lmax, off));
    if (lane == 0) red[wid] = lmax;
    __syncthreads();
    float gmax = fmaxf(fmaxf(red[0], red[1]), fmaxf(red[2], red[3]));
    float lsum = 0.f;
    for (int it = 0; it < SEQ / 256; ++it) {
        int s = it * 256 + tid;
        float p = __expf(e_lds[s] - gmax);
        e_lds[s] = p;
        lsum += p;
    }
    for (int off = 32; off; off >>= 1) lsum += __shfl_xor(lsum, off);
    if (lane == 0) red2[wid] = lsum;
    __syncthreads();
    float inv = 1.f / (red2[0] + red2[1] + red2[2] + red2[3]);
    for (int it = 0; it < SEQ / 256; ++it) {
        int s = it * 256 + tid;
        out[(size_t)b * SEQ + s] = e_lds[s] * inv;
    }
}

extern "C" void kernel_launch(void* const* d_in, const int* in_sizes, int n_in,
                              void* d_out, int out_size, void* d_ws, size_t ws_size,
                              hipStream_t stream) {
    const float* hidden   = (const float*)d_in[0];
    const float* enc      = (const float*)d_in[1];
    const int*   seq_mask = (const int*)d_in[2];
    const float* attn_w   = (const float*)d_in[3];
    const float* attn_b   = (const float*)d_in[4];
    const float* score_w  = (const float*)d_in[5];
    float* out = (float*)d_out;

    char* ws = (char*)d_ws;
    float* q = (float*)ws;                                        // 64 KB
    __hip_bfloat16* web = (__hip_bfloat16*)(ws + 65536);          // 2 MB
    float* part = (float*)(ws + 65536 + 2 * 1024 * 1024);         // 512 KB
    __hip_bfloat16* encb = (__hip_bfloat16*)(ws + 65536 + 3 * 1024 * 1024);  // 64 MB

    prep_all<<<dim3(NB_ENC + NB_WE + NB_QK), dim3(256), 0, stream>>>(hidden, enc, attn_w, attn_b, q, web, encb);
    gemm8<<<dim3(NBLK * (M_TOT / BM)), dim3(512), 0, stream>>>(encb, web, q, score_w, part);
    softmax_kernel<<<dim3(BATCH), dim3(256), 0, stream>>>(part, seq_mask, out);
}

// Round 15
// 116.436 us; speedup vs baseline: 2.9698x; 1.0185x over previous
//
#include <hip/hip_runtime.h>
#include <hip/hip_bf16.h>

#define HDIM 1024
#define SEQ 2048
#define BATCH 16
#define M_TOT (SEQ*BATCH)   // 32768
#define NBLK 4              // N split into 4 chunks of 256
#define BM 256
#define BN 256
#define BKT 64              // K-tile depth
#define NT (HDIM/BKT)       // 16 K-tiles

// prep_all grid layout
#define NB_ENC ((M_TOT*HDIM)/(8*256))   // 16384
#define NB_WE  ((HDIM*HDIM)/(8*256))    // 512
#define NB_QK  (HDIM)                   // 1024

typedef __attribute__((ext_vector_type(8))) short short8;
typedef __attribute__((ext_vector_type(4))) float f32x4;

typedef const void __attribute__((address_space(1))) gvoid_t;
typedef void __attribute__((address_space(3))) svoid_t;
#define GLD16(gp, lp) __builtin_amdgcn_global_load_lds((gvoid_t*)(gp), (svoid_t*)(lp), 16, 0, 0)
#define VMC(N) asm volatile("s_waitcnt vmcnt(" #N ")" ::: "memory")

static __device__ __forceinline__ unsigned short f2bf(float f) {
    unsigned int x = __float_as_uint(f);
    unsigned int r = (x + 0x7FFFu + ((x >> 16) & 1u)) >> 16;  // RNE
    return (unsigned short)r;
}

// ---------------- kernel 1: fused prep = conv_enc + conv_we + qk ----------------
__global__ __launch_bounds__(256) void prep_all(const float* __restrict__ hidden,
                                                const float* __restrict__ enc,
                                                const float* __restrict__ attn_w,
                                                const float* __restrict__ attn_b,
                                                float* __restrict__ q,
                                                __hip_bfloat16* __restrict__ web,
                                                __hip_bfloat16* __restrict__ encb) {
    int bid = blockIdx.x;
    if (bid < NB_ENC) {
        size_t i0 = ((size_t)bid * 256 + threadIdx.x) * 8;
        const float4* s = reinterpret_cast<const float4*>(enc + i0);
        float4 a = s[0], b = s[1];
        union { unsigned short u[8]; short8 v; } cv;
        cv.u[0] = f2bf(a.x); cv.u[1] = f2bf(a.y); cv.u[2] = f2bf(a.z); cv.u[3] = f2bf(a.w);
        cv.u[4] = f2bf(b.x); cv.u[5] = f2bf(b.y); cv.u[6] = f2bf(b.z); cv.u[7] = f2bf(b.w);
        *reinterpret_cast<short8*>((unsigned short*)encb + i0) = cv.v;
        return;
    }
    if (bid < NB_ENC + NB_WE) {
        size_t i0 = ((size_t)(bid - NB_ENC) * 256 + threadIdx.x) * 8;
        int n = (int)(i0 >> 10);
        int h = (int)(i0 & 1023);
        const float4* src = reinterpret_cast<const float4*>(attn_w + (size_t)n * (2 * HDIM) + HDIM + h);
        float4 a = src[0], b = src[1];
        union { unsigned short u[8]; short8 v; } cv;
        cv.u[0] = f2bf(a.x); cv.u[1] = f2bf(a.y); cv.u[2] = f2bf(a.z); cv.u[3] = f2bf(a.w);
        cv.u[4] = f2bf(b.x); cv.u[5] = f2bf(b.y); cv.u[6] = f2bf(b.z); cv.u[7] = f2bf(b.w);
        *reinterpret_cast<short8*>((unsigned short*)web + i0) = cv.v;
        return;
    }
    int k = bid - (NB_ENC + NB_WE);   // 0..1023
    int tid = threadIdx.x;
    const float* w = attn_w + (size_t)k * (2 * HDIM);
    float p[BATCH];
#pragma unroll
    for (int b = 0; b < BATCH; b++) p[b] = 0.f;
    for (int h = tid; h < HDIM; h += 256) {
        float wv = w[h];
#pragma unroll
        for (int b = 0; b < BATCH; b++) p[b] += hidden[b * HDIM + h] * wv;
    }
#pragma unroll
    for (int b = 0; b < BATCH; b++) {
        for (int off = 32; off; off >>= 1) p[b] += __shfl_down(p[b], off);
    }
    __shared__ float red[4][BATCH];
    int lane = tid & 63, wid = tid >> 6;
    if (lane == 0) {
#pragma unroll
        for (int b = 0; b < BATCH; b++) red[wid][b] = p[b];
    }
    __syncthreads();
    if (tid < BATCH) {
        float s = red[0][tid] + red[1][tid] + red[2][tid] + red[3][tid] + attn_b[k];
        q[(size_t)tid * HDIM + k] = s;
    }
}

// ---------------- kernel 2: 256x256 GEMM, 1 barrier/tile (B triple-buffered) ----------------
// LDS map (bytes): A[par][half] = par*32768 + half*16384 (64KB);
//                  B[buf][half] = 65536 + buf*32768 + half*16384, buf in 0..2 (96KB). 160KB total.
// Swizzle involution within each 128B row: byte ^= ((row&7)<<4). Applied to global src + ds_read.
// Per tile t: read B(t) from B[t%3] (regs) + A(t) from A[t&1]; stage A(t+1)->A[par^1],
// B(t+2)->B[(t+2)%3] (never the live/next buffer -> NO interior barrier needed).
// Close: VMC(4) (drains A(t+1)+B(t+1), keeps B(t+2) in flight) + one s_barrier.
// Epilogue: LDS-transpose reduce (padded [4][256][20]) instead of 128 shfl_xor per wave.
__global__ __launch_bounds__(512, 2) void gemm8(const __hip_bfloat16* __restrict__ encb,
                                                const __hip_bfloat16* __restrict__ web,
                                                const float* __restrict__ qv,
                                                const float* __restrict__ score_w,
                                                float* __restrict__ part) {
    __shared__ __align__(16) char pool[163840];

    int tid = threadIdx.x;
    int lane = tid & 63;
    int wid = tid >> 6;        // 0..7
    int wr = wid >> 2;         // 0..1  M half
    int wc = wid & 3;          // 0..3  N quarter

    // XCD-bijective swizzle: 512 blocks = 8 XCDs x 64; same-bm (A-panel) blocks contiguous per XCD
    int bid = blockIdx.x;
    int lin = (bid & 7) * 64 + (bid >> 3);
    int bm = lin >> 2;         // 0..127
    int bn = lin & 3;          // 0..3
    int m0 = bm * BM, n0 = bn * BN;

    // ---- staging thread constants (pre-swizzled global source) ----
    int srow = tid >> 3;                                   // 0..63
    int scolb = (((tid & 7) ^ ((tid >> 3) & 7)) << 4);     // swizzled byte col 0..127
    const char* eb = (const char*)encb;
    const char* wb = (const char*)web;

    auto STG = [&](const char* g, int ldsoff) {
        GLD16(g + (size_t)srow * 2048 + scolb, pool + ldsoff + wid * 1024);
        GLD16(g + (size_t)(srow + 64) * 2048 + scolb, pool + ldsoff + 8192 + wid * 1024);
    };
    auto APTR = [&](int kt, int h) { return eb + ((size_t)(m0 + h * 128) * HDIM + kt * BKT) * 2; };
    auto BPTR = [&](int kt, int h) { return wb + ((size_t)(n0 + h * 128) * HDIM + kt * BKT) * 2; };
#define ALDS(par, h) ((par) * 32768 + (h) * 16384)
#define BLDS(buf, h) (65536 + (buf) * 32768 + (h) * 16384)

    // ---- fragment-read constants (swizzled ds_read addresses) ----
    int lq = lane & 15, lh = lane >> 4;
    int flip = (lane & 7) << 4;
    int pks0 = lq * 128 + ((lh * 16) ^ flip);
    int pks1 = lq * 128 + (((64 + lh * 16)) ^ flip);
    int aFB = wr * 16384;                                   // + par*32768
    int bOFF = (wc >> 1) * 16384 + (wc & 1) * 8192;         // within B buffer

    f32x4 acc[8][4];
#pragma unroll
    for (int i = 0; i < 8; i++)
#pragma unroll
        for (int j = 0; j < 4; j++) acc[i][j] = (f32x4)0.f;
    short8 br[4][2];

#define RD8(off) (*reinterpret_cast<const short8*>(pool + (off)))

    // cluster Q of tile: frag reads (B full at Q==0 from buf BB) + stage + 16 MFMA. No barriers.
#define CLUSTER(Q, PAR, BB, STAGE_STMT)                                                   \
    {                                                                                     \
        if ((Q) == 0) {                                                                   \
            _Pragma("unroll") for (int nj = 0; nj < 4; ++nj) {                            \
                br[nj][0] = RD8(65536 + (BB) * 32768 + bOFF + nj * 2048 + pks0);          \
                br[nj][1] = RD8(65536 + (BB) * 32768 + bOFF + nj * 2048 + pks1);          \
            }                                                                             \
        }                                                                                 \
        short8 a0k0 = RD8(aFB + (PAR) * 32768 + (2 * (Q)) * 2048 + pks0);                 \
        short8 a0k1 = RD8(aFB + (PAR) * 32768 + (2 * (Q)) * 2048 + pks1);                 \
        short8 a1k0 = RD8(aFB + (PAR) * 32768 + (2 * (Q) + 1) * 2048 + pks0);             \
        short8 a1k1 = RD8(aFB + (PAR) * 32768 + (2 * (Q) + 1) * 2048 + pks1);             \
        STAGE_STMT;                                                                       \
        __builtin_amdgcn_s_setprio(1);                                                    \
        _Pragma("unroll") for (int nj = 0; nj < 4; ++nj) {                                \
            acc[2 * (Q)][nj] = __builtin_amdgcn_mfma_f32_16x16x32_bf16(a0k0, br[nj][0], acc[2 * (Q)][nj], 0, 0, 0); \
            acc[2 * (Q)][nj] = __builtin_amdgcn_mfma_f32_16x16x32_bf16(a0k1, br[nj][1], acc[2 * (Q)][nj], 0, 0, 0); \
            acc[2 * (Q) + 1][nj] = __builtin_amdgcn_mfma_f32_16x16x32_bf16(a1k0, br[nj][0], acc[2 * (Q) + 1][nj], 0, 0, 0); \
            acc[2 * (Q) + 1][nj] = __builtin_amdgcn_mfma_f32_16x16x32_bf16(a1k1, br[nj][1], acc[2 * (Q) + 1][nj], 0, 0, 0); \
        }                                                                                 \
        __builtin_amdgcn_s_setprio(0);                                                    \
    }

    // tile = 4 barrier-free clusters + close {counted VMC; one barrier}
#define TILE(PAR, BB, S1, S2, S3, S4, CLOSE)                                              \
    {                                                                                     \
        CLUSTER(0, PAR, BB, S1);                                                          \
        CLUSTER(1, PAR, BB, S2);                                                          \
        CLUSTER(2, PAR, BB, S3);                                                          \
        CLUSTER(3, PAR, BB, S4);                                                          \
        CLOSE;                                                                            \
        __builtin_amdgcn_s_barrier();                                                     \
        __builtin_amdgcn_sched_barrier(0);                                                \
    }

    // ---- prologue: stage A(0), B(0), B(1); land A(0)+B(0), keep B(1) in flight ----
    STG(APTR(0, 0), ALDS(0, 0));
    STG(APTR(0, 1), ALDS(0, 1));
    STG(BPTR(0, 0), BLDS(0, 0));
    STG(BPTR(0, 1), BLDS(0, 1));
    STG(BPTR(1, 0), BLDS(1, 0));
    STG(BPTR(1, 1), BLDS(1, 1));
    VMC(4);
    __builtin_amdgcn_s_barrier();
    __builtin_amdgcn_sched_barrier(0);

    // ---- main loop: 2 x 6 tiles (pattern period lcm(2,3)=6), then 4 peeled ----
#pragma unroll 1
    for (int J = 0; J < 2; ++J) {
        int t = 6 * J;
        TILE(0, 0, STG(APTR(t + 1, 0), ALDS(1, 0)), STG(APTR(t + 1, 1), ALDS(1, 1)),
                   STG(BPTR(t + 2, 0), BLDS(2, 0)), STG(BPTR(t + 2, 1), BLDS(2, 1)), VMC(4));
        TILE(1, 1, STG(APTR(t + 2, 0), ALDS(0, 0)), STG(APTR(t + 2, 1), ALDS(0, 1)),
                   STG(BPTR(t + 3, 0), BLDS(0, 0)), STG(BPTR(t + 3, 1), BLDS(0, 1)), VMC(4));
        TILE(0, 2, STG(APTR(t + 3, 0), ALDS(1, 0)), STG(APTR(t + 3, 1), ALDS(1, 1)),
                   STG(BPTR(t + 4, 0), BLDS(1, 0)), STG(BPTR(t + 4, 1), BLDS(1, 1)), VMC(4));
        TILE(1, 0, STG(APTR(t + 4, 0), ALDS(0, 0)), STG(APTR(t + 4, 1), ALDS(0, 1)),
                   STG(BPTR(t + 5, 0), BLDS(2, 0)), STG(BPTR(t + 5, 1), BLDS(2, 1)), VMC(4));
        TILE(0, 1, STG(APTR(t + 5, 0), ALDS(1, 0)), STG(APTR(t + 5, 1), ALDS(1, 1)),
                   STG(BPTR(t + 6, 0), BLDS(0, 0)), STG(BPTR(t + 6, 1), BLDS(0, 1)), VMC(4));
        TILE(1, 2, STG(APTR(t + 6, 0), ALDS(0, 0)), STG(APTR(t + 6, 1), ALDS(0, 1)),
                   STG(BPTR(t + 7, 0), BLDS(1, 0)), STG(BPTR(t + 7, 1), BLDS(1, 1)), VMC(4));
    }
    // tiles 12..15
    TILE(0, 0, STG(APTR(13, 0), ALDS(1, 0)), STG(APTR(13, 1), ALDS(1, 1)),
               STG(BPTR(14, 0), BLDS(2, 0)), STG(BPTR(14, 1), BLDS(2, 1)), VMC(4));
    TILE(1, 1, STG(APTR(14, 0), ALDS(0, 0)), STG(APTR(14, 1), ALDS(0, 1)),
               STG(BPTR(15, 0), BLDS(0, 0)), STG(BPTR(15, 1), BLDS(0, 1)), VMC(4));
    TILE(0, 2, STG(APTR(15, 0), ALDS(1, 0)), STG(APTR(15, 1), ALDS(1, 1)), , , VMC(0));
    TILE(1, 0, , , , , );

    // ---- fused epilogue: LDS transpose-reduce (aliases pool; all K-loop buffers dead) ----
    float* q_lds = reinterpret_cast<float*>(pool);            // [16][256] 16KB
    float* sc_lds = reinterpret_cast<float*>(pool + 16384);   // [256] 1KB
    float* red = reinterpret_cast<float*>(pool + 17408);      // [4][256][20] f32 = 80KB
    {
        int qb = tid >> 5;            // 0..15
        int kl = (tid & 31) * 8;      // 0..248
        const float4* src = reinterpret_cast<const float4*>(qv + (size_t)qb * HDIM + n0 + kl);
        float4 v0 = src[0], v1 = src[1];
        *reinterpret_cast<float4*>(&q_lds[qb * 256 + kl]) = v0;
        *reinterpret_cast<float4*>(&q_lds[qb * 256 + kl + 4]) = v1;
        if (tid < BN) sc_lds[tid] = score_w[n0 + tid];
    }
    __syncthreads();

#pragma unroll
    for (int mi = 0; mi < 8; ++mi) {
#pragma unroll
        for (int r = 0; r < 4; ++r) {
            int b = lh * 4 + r;       // row-within-16 == batch index
            float s = 0.f;
#pragma unroll
            for (int nj = 0; nj < 4; ++nj) {
                int kl = wc * 64 + nj * 16 + lq;
                float v = acc[mi][nj][r] + q_lds[b * 256 + kl];
                float t = 1.f - 2.f / (__expf(2.f * v) + 1.f);  // tanh(v)
                s += sc_lds[kl] * t;
            }
            int row = wr * 128 + mi * 16 + b;
            red[(wc * 256 + row) * 20 + lq] = s;   // padded stride 20: banks spread, no tree shfl
        }
    }
    __syncthreads();
    if (tid < BM) {
        float t = 0.f;
#pragma unroll
        for (int w4 = 0; w4 < 4; ++w4) {
            const f32x4* p = reinterpret_cast<const f32x4*>(&red[(w4 * 256 + tid) * 20]);
#pragma unroll
            for (int i = 0; i < 4; ++i) {
                f32x4 v = p[i];
                t += v[0] + v[1] + v[2] + v[3];
            }
        }
        part[(size_t)bn * M_TOT + m0 + tid] = t;
    }
#undef CLUSTER
#undef TILE
#undef RD8
#undef ALDS
#undef BLDS
}

// ---------------- kernel 3: reduce partials + mask + softmax over S ----------------
__global__ __launch_bounds__(256) void softmax_kernel(const float* __restrict__ part,
                                                      const int* __restrict__ mask,
                                                      float* __restrict__ out) {
    int b = blockIdx.x;
    int tid = threadIdx.x;
    __shared__ float e_lds[SEQ];
    __shared__ float red[4], red2[4];
    int lane = tid & 63, wid = tid >> 6;
    float lmax = -3.4e38f;
    for (int it = 0; it < SEQ / 256; ++it) {
        int s = it * 256 + tid;
        size_t m = (size_t)s * BATCH + b;
        float e = 0.f;
#pragma unroll
        for (int c = 0; c < NBLK; c++) e += part[(size_t)c * M_TOT + m];
        if (mask[(size_t)b * SEQ + s]) e = -1e12f;
        e_lds[s] = e;
        lmax = fmaxf(lmax, e);
    }
    for (int off = 32; off; off >>= 1) lmax = fmaxf(lmax, __shfl_xor(lmax, off));
    if (lane == 0) red[wid] = lmax;
    __syncthreads();
    float gmax = fmaxf(fmaxf(red[0], red[1]), fmaxf(red[2], red[3]));
    float lsum = 0.f;
    for (int it = 0; it < SEQ / 256; ++it) {
        int s = it * 256 + tid;
        float p = __expf(e_lds[s] - gmax);
        e_lds[s] = p;
        lsum += p;
    }
    for (int off = 32; off; off >>= 1) lsum += __shfl_xor(lsum, off);
    if (lane == 0) red2[wid] = lsum;
    __syncthreads();
    float inv = 1.f / (red2[0] + red2[1] + red2[2] + red2[3]);
    for (int it = 0; it < SEQ / 256; ++it) {
        int s = it * 256 + tid;
        out[(size_t)b * SEQ + s] = e_lds[s] * inv;
    }
}

extern "C" void kernel_launch(void* const* d_in, const int* in_sizes, int n_in,
                              void* d_out, int out_size, void* d_ws, size_t ws_size,
                              hipStream_t stream) {
    const float* hidden   = (const float*)d_in[0];
    const float* enc      = (const float*)d_in[1];
    const int*   seq_mask = (const int*)d_in[2];
    const float* attn_w   = (const float*)d_in[3];
    const float* attn_b   = (const float*)d_in[4];
    const float* score_w  = (const float*)d_in[5];
    float* out = (float*)d_out;

    char* ws = (char*)d_ws;
    float* q = (float*)ws;                                        // 64 KB
    __hip_bfloat16* web = (__hip_bfloat16*)(ws + 65536);          // 2 MB
    float* part = (float*)(ws + 65536 + 2 * 1024 * 1024);         // 512 KB
    __hip_bfloat16* encb = (__hip_bfloat16*)(ws + 65536 + 3 * 1024 * 1024);  // 64 MB

    prep_all<<<dim3(NB_ENC + NB_WE + NB_QK), dim3(256), 0, stream>>>(hidden, enc, attn_w, attn_b, q, web, encb);
    gemm8<<<dim3(NBLK * (M_TOT / BM)), dim3(512), 0, stream>>>(encb, web, q, score_w, part);
    softmax_kernel<<<dim3(BATCH), dim3(256), 0, stream>>>(part, seq_mask, out);
}